// Round 12
// baseline (1634.694 us; speedup 1.0000x reference)
//
#include <hip/hip_runtime.h>
#include <hip/hip_bf16.h>
#include <hip/hip_fp16.h>

#define DZ 128
#define DB 32
#define DSIN 32
#define DX 64
#define NB 64
#define TT 4096

typedef short v8s __attribute__((ext_vector_type(8)));
typedef float v4f __attribute__((ext_vector_type(4)));
typedef _Float16 v2h __attribute__((ext_vector_type(2)));

// quad butterfly stages via DPP quad_perm (VALU pipe, intra-quad)
__device__ __forceinline__ float dpp_xor1(float x) {
  int y = __builtin_amdgcn_mov_dpp(__builtin_bit_cast(int, x), 0xB1, 0xF, 0xF, true);
  return __builtin_bit_cast(float, y);
}
__device__ __forceinline__ float dpp_xor2(float x) {
  int y = __builtin_amdgcn_mov_dpp(__builtin_bit_cast(int, x), 0x4E, 0xF, 0xF, true);
  return __builtin_bit_cast(float, y);
}

__device__ __forceinline__ short f2bf(float f) {
  __hip_bfloat16 h = __float2bfloat16(f);
  return *reinterpret_cast<short*>(&h);
}

// pack two f32 -> packed bf16 dword, single instruction
__device__ __forceinline__ unsigned cvt_pk_bf16(float lo, float hi) {
  unsigned r;
  asm volatile("v_cvt_pk_bf16_f32 %0, %1, %2" : "=v"(r) : "v"(lo), "v"(hi));
  return r;
}

__device__ __forceinline__ v2h pk2h(float a, float b) {
  return __builtin_bit_cast(v2h, __builtin_amdgcn_cvt_pkrtz(a, b));
}
__device__ __forceinline__ float fdot2(v2h a, v2h b, float c) {
  return __builtin_amdgcn_fdot2(a, b, c, false);
}

// --- kernel 0: WCd[i] = sum_{j != i} AW[i][j] * (sum_k alphas[k]*clip[j][k]) ---
__global__ void k_prep(const float* __restrict__ AW, const float* __restrict__ alphas,
                       const float* __restrict__ clip, float* __restrict__ WCd) {
  __shared__ float cd[DZ];
  int j = threadIdx.x;
  float s = 0.f;
  for (int k = 0; k < DB; ++k) s = fmaf(alphas[k], clip[j * DB + k], s);
  cd[j] = s;
  __syncthreads();
  float acc = 0.f;
  for (int jj = 0; jj < DZ; ++jj)
    if (jj != j) acc = fmaf(AW[j * DZ + jj], cd[jj], acc);
  WCd[j] = acc;
}

// --- kernel 1: UT[i][t] = h[i] - WCd[i] + sum_s C[i][s]*inp[t][s]  (transposed) ---
__global__ void k_u(const float* __restrict__ inp, const float* __restrict__ h,
                    const float* __restrict__ C, const float* __restrict__ WCd,
                    float* __restrict__ UT) {
  int gid = blockIdx.x * blockDim.x + threadIdx.x;  // 128 * 1024 threads
  int i = gid >> 10;
  int t0 = (gid & 1023) * 4;
  float base = h[i] - WCd[i];
  const float4* c4 = (const float4*)(C + i * DSIN);
  float4 cv[8];
#pragma unroll
  for (int s = 0; s < 8; ++s) cv[s] = c4[s];
  float out[4];
#pragma unroll
  for (int tt = 0; tt < 4; ++tt) {
    const float4* i4 = (const float4*)(inp + (size_t)(t0 + tt) * DSIN);
    float u = base;
#pragma unroll
    for (int s = 0; s < 8; ++s) {
      float4 iv = i4[s];
      u = fmaf(cv[s].x, iv.x, u);
      u = fmaf(cv[s].y, iv.y, u);
      u = fmaf(cv[s].z, iv.z, u);
      u = fmaf(cv[s].w, iv.w, u);
    }
    out[tt] = u;
  }
  *(float4*)(UT + (size_t)i * TT + t0) = make_float4(out[0], out[1], out[2], out[3]);
}

// --- kernel 2: sequential scan. One block per batch, 256 threads:
// lane owns a DIM PAIR p=tid>>2 (dims 2p,2p+1) and quad-slice s=tid&3
// (k-slice for basis, col-quarter for matvec). Each ds_read_b128 of packed g
// feeds TWO rows (reuse): per-CU DS reads halve vs round 11 (16 wave-insts).
// g exchanged as packed (g_2p, g_2p+1) f16 dwords; quad combine via 2 DPP
// stages. Per-lane: 32 basis inst, 4 b128 reads, 32 fdot2. 4 waves, 1/SIMD. ---
__global__ __launch_bounds__(256, 1) void k_scan(
    const float* __restrict__ z0, const float* __restrict__ AW,
    const float* __restrict__ thetas, const float* __restrict__ alphas,
    const float* __restrict__ clip, const float* __restrict__ UT,
    unsigned* __restrict__ Z32) {
  __shared__ __align__(16) unsigned gpk[2][64];  // packed f16 g pairs, dbuf, 512 B
  const int b = blockIdx.x;
  const int tid = threadIdx.x;
  const int p = tid >> 2, s = tid & 3;
  const int i0 = 2 * p, i1 = i0 + 1;
  const int c0 = 32 * s;

  // W rows i0,i1, cols [c0,c0+32) as 16 packed-f16 pairs each; diag zeroed.
  // col c0+2j is even, c0+2j+1 odd -> diag hits w0.x (i0 even) / w1.y (i1 odd)
  // under the same condition c0+2j == i0.
  v2h w0[16], w1[16];
#pragma unroll
  for (int j = 0; j < 16; ++j) {
    float2 a0 = *(const float2*)(AW + (size_t)i0 * DZ + c0 + 2 * j);
    float2 a1 = *(const float2*)(AW + (size_t)i1 * DZ + c0 + 2 * j);
    bool dg = (c0 + 2 * j == i0);
    w0[j] = pk2h(dg ? 0.f : a0.x, a0.y);
    w1[j] = pk2h(a1.x, dg ? 0.f : a1.y);
  }
  const float ad0 = AW[(size_t)i0 * DZ + i0], ad1 = AW[(size_t)i1 * DZ + i1];

  // basis: lane covers k in [8s, 8s+8) for both dims, as 4 packed pairs
  v2h th0[4], th1[4], nc0[4], nc1[4], al[4];
#pragma unroll
  for (int m = 0; m < 4; ++m) {
    int k = 8 * s + 2 * m;
    th0[m] = pk2h(thetas[i0 * DB + k], thetas[i0 * DB + k + 1]);
    th1[m] = pk2h(thetas[i1 * DB + k], thetas[i1 * DB + k + 1]);
    nc0[m] = pk2h(-clip[i0 * DB + k], -clip[i0 * DB + k + 1]);
    nc1[m] = pk2h(-clip[i1 * DB + k], -clip[i1 * DB + k + 1]);
    al[m] = pk2h(-0.82f * alphas[k], -0.82f * alphas[k + 1]);
  }

  float zA = z0[b * DZ + i0], zB = z0[b * DZ + i1];
  const float4* upA = (const float4*)(UT + (size_t)i0 * TT);
  const float4* upB = (const float4*)(UT + (size_t)i1 * TT);
  float4 ugA = upA[0], ugB = upB[0];
  unsigned* zp = Z32 + (size_t)b * 64 + p;  // packed (dim 2p, 2p+1) dwords
  const v2h zero2 = pk2h(0.f, 0.f);

#pragma unroll 1
  for (int tg = 0; tg < TT / 4; ++tg) {
    int tn = (tg + 1 < TT / 4) ? tg + 1 : tg;
    float4 ugAn = upA[tn], ugBn = upB[tn];  // prefetch next group
    float uA[4] = {ugA.x, ugA.y, ugA.z, ugA.w};
    float uB[4] = {ugB.x, ugB.y, ugB.z, ugB.w};
#pragma unroll
    for (int q = 0; q < 4; ++q) {
      unsigned* gq = gpk[q & 1];
      // basis for both dims over this lane's 8 k's (2 chains per dim)
      v2h zA2 = pk2h(zA, zA), zB2 = pk2h(zB, zB);
      float gA0 = 0.f, gA1 = 0.f, gB0 = 0.f, gB1 = 0.f;
#pragma unroll
      for (int m = 0; m < 4; m += 2) {
        v2h dA0 = __builtin_elementwise_min(
            __builtin_elementwise_max(zA2 - th0[m], nc0[m]), zero2);
        v2h dA1 = __builtin_elementwise_min(
            __builtin_elementwise_max(zA2 - th0[m + 1], nc0[m + 1]), zero2);
        v2h dB0 = __builtin_elementwise_min(
            __builtin_elementwise_max(zB2 - th1[m], nc1[m]), zero2);
        v2h dB1 = __builtin_elementwise_min(
            __builtin_elementwise_max(zB2 - th1[m + 1], nc1[m + 1]), zero2);
        gA0 = fdot2(al[m], dA0, gA0);
        gA1 = fdot2(al[m + 1], dA1, gA1);
        gB0 = fdot2(al[m], dB0, gB0);
        gB1 = fdot2(al[m + 1], dB1, gB1);
      }
      float gA = gA0 + gA1;
      gA += dpp_xor1(gA);
      gA += dpp_xor2(gA);
      float gB = gB0 + gB1;
      gB += dpp_xor1(gB);
      gB += dpp_xor2(gB);
      if (s == 0) gq[p] = __builtin_bit_cast(unsigned, pk2h(gA, gB));
      // drain LDS write, then barrier (no vmcnt drain: Z/U traffic keeps flying)
      asm volatile("s_waitcnt lgkmcnt(0)\n\ts_barrier" ::: "memory");

      // matvec quarter for both rows: pairs [16s,16s+16) -> 4 b128, 32 fdot2
      const uint4* g4 = ((const uint4*)gq) + 4 * s;
      float mA0 = 0.f, mA1 = 0.f, mA2 = 0.f, mA3 = 0.f;
      float mB0 = 0.f, mB1 = 0.f, mB2 = 0.f, mB3 = 0.f;
#pragma unroll
      for (int r = 0; r < 4; ++r) {
        uint4 qd = g4[r];
        v2h q0 = __builtin_bit_cast(v2h, qd.x), q1 = __builtin_bit_cast(v2h, qd.y);
        v2h q2 = __builtin_bit_cast(v2h, qd.z), q3 = __builtin_bit_cast(v2h, qd.w);
        mA0 = fdot2(w0[4 * r + 0], q0, mA0);
        mA1 = fdot2(w0[4 * r + 1], q1, mA1);
        mA2 = fdot2(w0[4 * r + 2], q2, mA2);
        mA3 = fdot2(w0[4 * r + 3], q3, mA3);
        mB0 = fdot2(w1[4 * r + 0], q0, mB0);
        mB1 = fdot2(w1[4 * r + 1], q1, mB1);
        mB2 = fdot2(w1[4 * r + 2], q2, mB2);
        mB3 = fdot2(w1[4 * r + 3], q3, mB3);
      }
      float mA = (mA0 + mA1) + (mA2 + mA3);
      mA += dpp_xor1(mA);
      mA += dpp_xor2(mA);
      float mB = (mB0 + mB1) + (mB2 + mB3);
      mB += dpp_xor1(mB);
      mB += dpp_xor2(mB);
      zA = fmaf(zA, ad0, mA + uA[q]);
      zB = fmaf(zB, ad1, mB + uB[q]);
      if (s == 0) zp[(size_t)(tg * 4 + q) * (NB * 64)] = cvt_pk_bf16(zA, zB);
    }
    ugA = ugAn;
    ugB = ugBn;
  }
}

// --- kernel 3: out = Z(bf16, 262144x128) @ B_obs(128x64) via MFMA 16x16x32 bf16 ---
__global__ __launch_bounds__(256) void k_obs(const short* __restrict__ Z,
                                             const float* __restrict__ Bo,
                                             float* __restrict__ out) {
  const int lane = threadIdx.x & 63;
  const int wv = threadIdx.x >> 6;
  const int rl = lane & 15;  // A row / C col index
  const int g = lane >> 4;   // k-group

  v8s bfr[4][4];
#pragma unroll
  for (int nt = 0; nt < 4; ++nt) {
#pragma unroll
    for (int ks = 0; ks < 4; ++ks) {
      v8s f;
#pragma unroll
      for (int m = 0; m < 8; ++m) {
        int k = ks * 32 + g * 8 + m;
        f[m] = f2bf(Bo[k * DX + nt * 16 + rl]);
      }
      bfr[nt][ks] = f;
    }
  }

#pragma unroll
  for (int it = 0; it < 4; ++it) {
    const int r0 = blockIdx.x * 256 + it * 64 + wv * 16;
    const short* zrow = Z + (size_t)(r0 + rl) * DZ;
    v8s afr[4];
#pragma unroll
    for (int ks = 0; ks < 4; ++ks)
      afr[ks] = *(const v8s*)(zrow + ks * 32 + g * 8);
    v4f acc[4];
#pragma unroll
    for (int nt = 0; nt < 4; ++nt) acc[nt] = (v4f){0.f, 0.f, 0.f, 0.f};
#pragma unroll
    for (int nt = 0; nt < 4; ++nt) {
#pragma unroll
      for (int ks = 0; ks < 4; ++ks)
        acc[nt] = __builtin_amdgcn_mfma_f32_16x16x32_bf16(afr[ks], bfr[nt][ks], acc[nt], 0, 0, 0);
    }
#pragma unroll
    for (int nt = 0; nt < 4; ++nt) {
#pragma unroll
      for (int q = 0; q < 4; ++q)
        out[(size_t)(r0 + g * 4 + q) * DX + nt * 16 + rl] = acc[nt][q];
    }
  }
}

extern "C" void kernel_launch(void* const* d_in, const int* in_sizes, int n_in,
                              void* d_out, int out_size, void* d_ws, size_t ws_size,
                              hipStream_t stream) {
  const float* z0 = (const float*)d_in[0];
  const float* inp = (const float*)d_in[1];
  const float* AW = (const float*)d_in[2];
  const float* h = (const float*)d_in[3];
  const float* thetas = (const float*)d_in[4];
  const float* alphas = (const float*)d_in[5];
  const float* clip = (const float*)d_in[6];
  const float* C = (const float*)d_in[7];
  const float* Bo = (const float*)d_in[8];
  float* out = (float*)d_out;

  char* ws = (char*)d_ws;
  float* WCd = (float*)ws;                                 // 512 B
  float* UT = (float*)(ws + 1024);                         // 128*TT f32 = 2 MiB
  short* Z = (short*)(ws + 1024 + (size_t)TT * DZ * 4);    // TT*64*128 bf16 = 64 MiB

  k_prep<<<1, 128, 0, stream>>>(AW, alphas, clip, WCd);
  k_u<<<(DZ * TT / 4) / 256, 256, 0, stream>>>(inp, h, C, WCd, UT);
  k_scan<<<NB, 256, 0, stream>>>(z0, AW, thetas, alphas, clip, UT, (unsigned*)Z);
  k_obs<<<(TT * NB) / 256, 256, 0, stream>>>(Z, Bo, out);
}